// Round 1
// baseline (465.261 us; speedup 1.0000x reference)
//
#include <hip/hip_runtime.h>

// ChipDetector: gray -> 5x5 gauss blur -> sobel_y -> abs -> 5x5 dilate -> bbox of >0.
// Reduced to: global separable blur+sobel, bbox of nonzero edges, expand by +-2.
// See session notes: per-tile zero-padding effects only OR-in extra positives,
// so the global-computation bbox is a subset of (and a.s. equal to) the ref bbox.

constexpr int H = 4096, W = 4096;
constexpr int OH = 32, OW = 128;       // output tile per block
constexpr int GY = OH + 6;             // 38: gray rows needed (halo 3)
constexpr int GX = OW + 6;             // 134: gray cols needed
constexpr int BX = OW + 2;             // 130: blurred cols needed (sobel halo 1)
constexpr int BY = OH + 2;             // 34: blurred rows needed
constexpr int NT = 256;
constexpr int IMAX = 2147483647;

__global__ void init_ws(int* ws) {
    ws[0] = IMAX;  // ymin
    ws[1] = -1;    // ymax
    ws[2] = IMAX;  // xmin
    ws[3] = -1;    // xmax
}

__launch_bounds__(NT)
__global__ void edge_kernel(const float* __restrict__ x,
                            const float* __restrict__ gw,
                            int* __restrict__ ws) {
    __shared__ float A[GY * GX];   // gray tile, later reused as blurred [BY][BX]
    __shared__ float B[GY * BX];   // h-blur, later reused as sobel-h [BY][OW]
    __shared__ int s_miny, s_maxy, s_minx, s_maxx;

    const int tid = threadIdx.x;
    const int bx = blockIdx.x, by = blockIdx.y;
    const int gy0 = by * OH - 3;
    const int gx0 = bx * OW - 3;

    const float w0 = gw[0], w1 = gw[1], w2 = gw[2];

    if (tid == 0) { s_miny = IMAX; s_maxy = -1; s_minx = IMAX; s_maxx = -1; }

    const float* __restrict__ x0 = x;
    const float* __restrict__ x1 = x + (size_t)H * W;
    const float* __restrict__ x2 = x + 2 * (size_t)H * W;

    // --- gray tile (zero outside image) ---
    for (int i = tid; i < GY * GX; i += NT) {
        int ly = i / GX, lx = i - ly * GX;
        int gy = gy0 + ly, gx = gx0 + lx;
        float v = 0.f;
        if (gy >= 0 && gy < H && gx >= 0 && gx < W) {
            size_t idx = (size_t)gy * W + gx;
            v = w0 * x0[idx] + w1 * x1[idx] + w2 * x2[idx];
        }
        A[i] = v;
    }
    __syncthreads();

    // --- horizontal gaussian [1,4,6,4,1]/16; col c is global col bx*OW + c - 1 ---
    for (int i = tid; i < GY * BX; i += NT) {
        int ly = i / BX, c = i - ly * BX;
        int gcol = gx0 + 2 + c;  // bx*OW + c - 1
        float v = 0.f;
        if (gcol >= 0 && gcol < W) {
            const float* row = &A[ly * GX + c];
            v = 0.0625f * (row[0] + row[4]) + 0.25f * (row[1] + row[3]) + 0.375f * row[2];
        }
        B[i] = v;
    }
    __syncthreads();

    // --- vertical gaussian into A (blurred[BY][BX]); row r is global row by*OH + r - 1 ---
    // Blur values outside the image must be ZERO (reference sobel reads zero-padded
    // blurred), hence the explicit zeroing instead of letting the conv run over pad.
    for (int i = tid; i < BY * BX; i += NT) {
        int r = i / BX, c = i - r * BX;
        int grow = gy0 + 2 + r;  // by*OH + r - 1
        float v = 0.f;
        if (grow >= 0 && grow < H) {
            const float* col = &B[r * BX + c];
            v = 0.0625f * (col[0] + col[4 * BX]) + 0.25f * (col[BX] + col[3 * BX])
              + 0.375f * col[2 * BX];
        }
        A[i] = v;
    }
    __syncthreads();

    // --- horizontal sobel [1,2,1] into B (sh[BY][OW]) ---
    for (int i = tid; i < BY * OW; i += NT) {
        int r = i / OW, c = i - r * OW;
        const float* row = &A[r * BX + c];
        B[i] = row[0] + 2.f * row[1] + row[2];
    }
    __syncthreads();

    // --- vertical sobel [1,0,-1] + nonzero bbox reduction ---
    int lminy = IMAX, lmaxy = -1, lminx = IMAX, lmaxx = -1;
    for (int p = tid; p < OH * OW; p += NT) {
        int yy = p >> 7;            // OW == 128
        int xx = p & (OW - 1);
        float e = B[yy * OW + xx] - B[(yy + 2) * OW + xx];
        if (e != 0.f) {
            lminy = min(lminy, yy); lmaxy = max(lmaxy, yy);
            lminx = min(lminx, xx); lmaxx = max(lmaxx, xx);
        }
    }
    if (lmaxy >= 0) {
        atomicMin(&s_miny, lminy); atomicMax(&s_maxy, lmaxy);
        atomicMin(&s_minx, lminx); atomicMax(&s_maxx, lmaxx);
    }
    __syncthreads();
    if (tid == 0 && s_maxy >= 0) {
        atomicMin(&ws[0], by * OH + s_miny);
        atomicMax(&ws[1], by * OH + s_maxy);
        atomicMin(&ws[2], bx * OW + s_minx);
        atomicMax(&ws[3], bx * OW + s_maxx);
    }
}

__global__ void finalize(const int* __restrict__ ws, float* __restrict__ out) {
    int ymin = ws[0], ymax = ws[1], xmin = ws[2], xmax = ws[3];
    if (ymax < 0) {
        out[0] = 0.f; out[1] = 0.f; out[2] = 0.f; out[3] = 0.f;
    } else {
        // dilation by 2 (clipped to image), then ref's exclusive max (+1)
        out[0] = (float)(xmin - 2 > 0 ? xmin - 2 : 0);
        out[1] = (float)(ymin - 2 > 0 ? ymin - 2 : 0);
        out[2] = (float)((xmax + 2 < W - 1 ? xmax + 2 : W - 1) + 1);
        out[3] = (float)((ymax + 2 < H - 1 ? ymax + 2 : H - 1) + 1);
    }
}

extern "C" void kernel_launch(void* const* d_in, const int* in_sizes, int n_in,
                              void* d_out, int out_size, void* d_ws, size_t ws_size,
                              hipStream_t stream) {
    const float* x  = (const float*)d_in[0];   // (1,3,4096,4096) fp32
    const float* gw = (const float*)d_in[1];   // (3,) gray weights
    int*   ws  = (int*)d_ws;
    float* out = (float*)d_out;

    init_ws<<<1, 1, 0, stream>>>(ws);
    dim3 grid(W / OW, H / OH);  // 32 x 128 = 4096 blocks
    edge_kernel<<<grid, NT, 0, stream>>>(x, gw, ws);
    finalize<<<1, 1, 0, stream>>>(ws, out);
}

// Round 2
// 364.373 us; speedup vs baseline: 1.2769x; 1.2769x over previous
//
#include <hip/hip_runtime.h>

// ChipDetector: gray -> 5x5 gauss -> sobel_y -> |.| -> 5x5 dilate -> bbox of >0.
// Reduced to: bbox of nonzero sobel(blur(gray)) expanded by +-2 (dilation only
// moves the bbox by 2, scatter-add of tiles only ORs positives; per-tile padding
// adds positives only, so global computation gives the same bbox a.s.).
//
// R2: row-streaming separable pipeline. Vertical gauss in registers (sliding
// 5-window per column), one 262-float LDS row exchange per row (double-buffered,
// 1 sync/row), combined horizontal 7-tap (gauss*sobel_x) with exact boundary
// corrections, vertical sobel as a 2-deep register delay line. LDS 40KB->2KB.

constexpr int H = 4096, W = 4096;
constexpr int TCOLS = 256;           // columns per block (== threads)
constexpr int TROWS = 64;            // output rows per block
constexpr int NT = 256;
constexpr int BUFW = TCOLS + 6;      // 262 vg columns (x halo 3)
constexpr int IMAX = 2147483647;

__global__ void init_ws(int* ws) {
    ws[0] = IMAX;  // ymin
    ws[1] = -1;    // ymax
    ws[2] = IMAX;  // xmin
    ws[3] = -1;    // xmax
}

__launch_bounds__(NT)
__global__ void edge_kernel(const float* __restrict__ x,
                            const float* __restrict__ gw,
                            int* __restrict__ ws) {
    __shared__ float vgbuf[2][BUFW + 2];   // +2 pad
    __shared__ int s_miny, s_maxy, s_minx, s_maxx;

    const int tid = threadIdx.x;
    const int x0 = blockIdx.x * TCOLS;
    const int y0 = blockIdx.y * TROWS;

    if (tid == 0) { s_miny = IMAX; s_maxy = -1; s_minx = IMAX; s_maxx = -1; }

    const float w0 = gw[0], w1 = gw[1], w2 = gw[2];
    const float* __restrict__ p0 = x;
    const float* __restrict__ p1 = x + (size_t)H * W;
    const float* __restrict__ p2 = x + 2 * (size_t)H * W;

    const int cm = x0 + tid;                       // main column (always in range)
    // 6 halo columns: threads 0..2 -> x0-3..x0-1 ; threads 253..255 -> x0+256..x0+258
    const bool hasx = (tid < 3) | (tid >= TCOLS - 3);
    const int ce = (tid < 3) ? (x0 - 3 + tid) : (x0 + 3 + tid);   // tid+3+x0 for right side
    const bool cev = hasx & (ce >= 0) & (ce < W);
    const int bi_main = tid + 3;
    const int bi_extra = (tid < 3) ? tid : (tid + 6);

    auto loadg = [&](int r, int c, bool valid) -> float {
        if (!valid || r < 0 || r >= H) return 0.f;
        size_t idx = (size_t)r * W + c;
        return w0 * p0[idx] + w1 * p1[idx] + w2 * p2[idx];
    };

    // preload gray rows y0-3 .. y0+1 into the vertical windows
    float g[5], ge[5];
    #pragma unroll
    for (int j = 0; j < 5; ++j) {
        int r = y0 - 3 + j;
        g[j]  = loadg(r, cm, true);
        ge[j] = hasx ? loadg(r, ce, cev) : 0.f;
    }

    // vertical gauss [1,4,6,4,1]/16 ; horizontal composite [1,6,15,20,15,6,1]/16
    constexpr float k0 = 0.0625f, k1 = 0.25f, k2 = 0.375f;
    constexpr float m0 = 0.0625f, m1 = 0.375f, m2 = 0.9375f, m3 = 1.25f;

    float sm1 = 0.f, sm2 = 0.f;        // S(yv-1), S(yv-2) (row-clipped)
    int gminy = IMAX, gmaxy = -1;
    bool anyhit = false;

    // yv = y0-1+it : rows where S is produced; e(yv-1) emitted for it>=2
    for (int it = 0; it < TROWS + 2; ++it) {
        const int yv = y0 - 1 + it;

        // prefetch gray row yv+3 (consumed at the window shift below)
        const int rn = yv + 3;
        float nm = loadg(rn, cm, true);
        float ne = hasx ? loadg(rn, ce, cev) : 0.f;

        // vertical gauss for row yv
        float* buf = vgbuf[it & 1];
        buf[bi_main] = k0 * (g[0] + g[4]) + k1 * (g[1] + g[3]) + k2 * g[2];
        if (hasx)
            buf[bi_extra] = k0 * (ge[0] + ge[4]) + k1 * (ge[1] + ge[3]) + k2 * ge[2];
        __syncthreads();

        // horizontal: S(yv, cm) = sobel_x(clip(gauss_x(vg)))
        float S = 0.f;
        if (yv >= 0 && yv < H) {
            const float* b = &buf[tid];
            S = m0 * (b[0] + b[6]) + m1 * (b[1] + b[5]) + m2 * (b[2] + b[4]) + m3 * b[3];
            // reference zero-clips blurred at image cols before sobel_x:
            if (cm == 0)     S -= 0.25f * b[3] + 0.0625f * b[4];   // phantom blur(-1)
            if (cm == W - 1) S -= 0.25f * b[3] + 0.0625f * b[2];   // phantom blur(W)
        }

        // vertical sobel [1,0,-1] with S row-clipped: e(yv-1) = S(yv-2) - S(yv)
        if (it >= 2) {
            float e = sm2 - S;
            if (e != 0.f) {
                int yy = yv - 1;
                gminy = min(gminy, yy);
                gmaxy = yy;
                anyhit = true;
            }
        }
        sm2 = sm1; sm1 = S;

        // shift vertical windows
        g[0] = g[1]; g[1] = g[2]; g[2] = g[3]; g[3] = g[4]; g[4] = nm;
        if (hasx) { ge[0] = ge[1]; ge[1] = ge[2]; ge[2] = ge[3]; ge[3] = ge[4]; ge[4] = ne; }
    }

    if (anyhit) {
        atomicMin(&s_miny, gminy); atomicMax(&s_maxy, gmaxy);
        atomicMin(&s_minx, cm);    atomicMax(&s_maxx, cm);
    }
    __syncthreads();
    if (tid == 0 && s_maxy >= 0) {
        atomicMin(&ws[0], s_miny);
        atomicMax(&ws[1], s_maxy);
        atomicMin(&ws[2], s_minx);
        atomicMax(&ws[3], s_maxx);
    }
}

__global__ void finalize(const int* __restrict__ ws, float* __restrict__ out) {
    int ymin = ws[0], ymax = ws[1], xmin = ws[2], xmax = ws[3];
    if (ymax < 0) {
        out[0] = 0.f; out[1] = 0.f; out[2] = 0.f; out[3] = 0.f;
    } else {
        // dilation by 2 (clipped), then ref's exclusive max (+1)
        out[0] = (float)(xmin - 2 > 0 ? xmin - 2 : 0);
        out[1] = (float)(ymin - 2 > 0 ? ymin - 2 : 0);
        out[2] = (float)((xmax + 2 < W - 1 ? xmax + 2 : W - 1) + 1);
        out[3] = (float)((ymax + 2 < H - 1 ? ymax + 2 : H - 1) + 1);
    }
}

extern "C" void kernel_launch(void* const* d_in, const int* in_sizes, int n_in,
                              void* d_out, int out_size, void* d_ws, size_t ws_size,
                              hipStream_t stream) {
    const float* xp = (const float*)d_in[0];   // (1,3,4096,4096) fp32
    const float* gw = (const float*)d_in[1];   // (3,) gray weights
    int*   ws  = (int*)d_ws;
    float* out = (float*)d_out;

    init_ws<<<1, 1, 0, stream>>>(ws);
    dim3 grid(W / TCOLS, H / TROWS);  // 16 x 64 = 1024 blocks
    edge_kernel<<<grid, NT, 0, stream>>>(xp, gw, ws);
    finalize<<<1, 1, 0, stream>>>(ws, out);
}

// Round 3
// 338.800 us; speedup vs baseline: 1.3733x; 1.0755x over previous
//
#include <hip/hip_runtime.h>

// ChipDetector: gray -> 5x5 gauss -> sobel_y -> |.| -> 5x5 dilate -> bbox of >0.
// Reduced to: bbox of nonzero sobel(blur(gray)) expanded by +-2 (see R1 notes:
// dilation shifts bbox by 2; tile scatter-add only ORs positives; per-tile
// padding only adds positives -> global computation gives the same bbox a.s.).
//
// R3: barrier-free wave pipeline. Each lane owns 4 columns (float4 loads,
// 48 B/lane/iter in flight); horizontal 7-tap halo via __shfl from neighbor
// lanes; wave-edge lanes keep a predicated extra halo column-group. No
// __syncthreads in the hot loop -> waves free-run, latency hidden by TLP+ILP.

constexpr int H = 4096, W = 4096;
constexpr int NT = 256;             // 4 waves per block
constexpr int WCOLS = 256;          // columns per wave (64 lanes x 4)
constexpr int TROWS = 16;           // output rows per wave
constexpr int IMAX = 2147483647;

__global__ void init_ws(int* ws) {
    ws[0] = IMAX;  // ymin
    ws[1] = -1;    // ymax
    ws[2] = IMAX;  // xmin
    ws[3] = -1;    // xmax
}

__device__ __forceinline__ float4 f4_zero() { return make_float4(0.f, 0.f, 0.f, 0.f); }

__launch_bounds__(NT, 4)
__global__ void edge_kernel(const float* __restrict__ x,
                            const float* __restrict__ gw,
                            int* __restrict__ ws) {
    __shared__ int s_miny, s_maxy, s_minx, s_maxx;

    const int tid  = threadIdx.x;
    const int lane = tid & 63;
    const int wid  = tid >> 6;

    if (tid == 0) { s_miny = IMAX; s_maxy = -1; s_minx = IMAX; s_maxx = -1; }
    __syncthreads();

    const int wx0 = (blockIdx.x * 4 + wid) * WCOLS;   // wave's column base
    const int y0  = blockIdx.y * TROWS;
    const int cm  = wx0 + lane * 4;                   // lane's first column

    const float w0 = gw[0], w1 = gw[1], w2 = gw[2];
    const float* __restrict__ p0 = x;
    const float* __restrict__ p1 = x + (size_t)H * W;
    const float* __restrict__ p2 = x + 2 * (size_t)H * W;

    // wave-edge halo column-group (4 cols): lane 0 -> wx0-4..wx0-1, lane 63 -> wx0+256..+259
    const bool haloL = (lane == 0), haloR = (lane == 63);
    const bool hasx  = haloL | haloR;
    const int  ce    = haloL ? (wx0 - 4) : (wx0 + WCOLS);
    const bool cev   = hasx & (ce >= 0) & (ce < W);   // float4 group all-in or all-out

    auto loadg4 = [&](int r, int c, bool valid) -> float4 {
        if (!valid || r < 0 || r >= H) return f4_zero();
        size_t idx = (size_t)r * W + c;
        float4 a = *reinterpret_cast<const float4*>(p0 + idx);
        float4 b = *reinterpret_cast<const float4*>(p1 + idx);
        float4 d = *reinterpret_cast<const float4*>(p2 + idx);
        return make_float4(w0 * a.x + w1 * b.x + w2 * d.x,
                           w0 * a.y + w1 * b.y + w2 * d.y,
                           w0 * a.z + w1 * b.z + w2 * d.z,
                           w0 * a.w + w1 * b.w + w2 * d.w);
    };

    // preload gray rows y0-3 .. y0+1 into vertical 5-windows
    float4 g[5], ge[5];
    #pragma unroll
    for (int j = 0; j < 5; ++j) {
        int r = y0 - 3 + j;
        g[j]  = loadg4(r, cm, true);
        ge[j] = hasx ? loadg4(r, ce, cev) : f4_zero();
    }

    // vertical gauss [1,4,6,4,1]/16 ; horizontal composite gauss*[1,2,1] taps
    constexpr float k0 = 0.0625f, k1 = 0.25f, k2 = 0.375f;
    constexpr float m0 = 0.0625f, m1 = 0.375f, m2 = 0.9375f, m3 = 1.25f;

    float4 sm1 = f4_zero(), sm2 = f4_zero();   // S(yv-1), S(yv-2)
    int gminy = IMAX, gmaxy = -1;
    unsigned hits = 0;                          // bit j: column cm+j ever hit

    for (int it = 0; it < TROWS + 2; ++it) {
        const int yv = y0 - 1 + it;

        // prefetch gray row yv+3 (consumed at the shift below)
        float4 nm = f4_zero(), ne = f4_zero();
        if (it <= TROWS) {
            nm = loadg4(yv + 3, cm, true);
            if (hasx) ne = loadg4(yv + 3, ce, cev);
        }

        float4 S = f4_zero();
        if (yv >= 0 && yv < H) {   // wave-uniform branch (shuffles inside are safe)
            // vertical gauss for row yv
            float4 vg = make_float4(
                k0 * (g[0].x + g[4].x) + k1 * (g[1].x + g[3].x) + k2 * g[2].x,
                k0 * (g[0].y + g[4].y) + k1 * (g[1].y + g[3].y) + k2 * g[2].y,
                k0 * (g[0].z + g[4].z) + k1 * (g[1].z + g[3].z) + k2 * g[2].z,
                k0 * (g[0].w + g[4].w) + k1 * (g[1].w + g[3].w) + k2 * g[2].w);

            // neighbor halo via shuffles (intra-wave, no barrier)
            float L1 = __shfl_up(vg.w, 1);     // col cm-1
            float L2 = __shfl_up(vg.z, 1);     // col cm-2
            float L3 = __shfl_up(vg.y, 1);     // col cm-3
            float R1 = __shfl_down(vg.x, 1);   // col cm+4
            float R2 = __shfl_down(vg.y, 1);   // col cm+5
            float R3 = __shfl_down(vg.z, 1);   // col cm+6
            if (hasx) {
                float vge_x = k0 * (ge[0].x + ge[4].x) + k1 * (ge[1].x + ge[3].x) + k2 * ge[2].x;
                float vge_y = k0 * (ge[0].y + ge[4].y) + k1 * (ge[1].y + ge[3].y) + k2 * ge[2].y;
                float vge_z = k0 * (ge[0].z + ge[4].z) + k1 * (ge[1].z + ge[3].z) + k2 * ge[2].z;
                float vge_w = k0 * (ge[0].w + ge[4].w) + k1 * (ge[1].w + ge[3].w) + k2 * ge[2].w;
                if (haloL) { L1 = vge_w; L2 = vge_z; L3 = vge_y; }
                else       { R1 = vge_x; R2 = vge_y; R3 = vge_z; }
            }

            // a0..a9 = vg at cols cm-3 .. cm+6
            float a0 = L3, a1 = L2, a2 = L1;
            float a3 = vg.x, a4 = vg.y, a5 = vg.z, a6 = vg.w;
            float a7 = R1, a8 = R2, a9 = R3;

            S.x = m0 * (a0 + a6) + m1 * (a1 + a5) + m2 * (a2 + a4) + m3 * a3;
            S.y = m0 * (a1 + a7) + m1 * (a2 + a6) + m2 * (a3 + a5) + m3 * a4;
            S.z = m0 * (a2 + a8) + m1 * (a3 + a7) + m2 * (a4 + a6) + m3 * a5;
            S.w = m0 * (a3 + a9) + m1 * (a4 + a8) + m2 * (a5 + a7) + m3 * a6;

            // reference zero-clips blurred at image columns before sobel_x:
            if (cm == 0)         S.x -= 0.25f * a3 + 0.0625f * a4;  // phantom blur(-1)
            if (cm + 3 == W - 1) S.w -= 0.25f * a6 + 0.0625f * a5;  // phantom blur(W)
        }

        // vertical sobel [1,0,-1] with row-clipped S: e(yv-1) = S(yv-2) - S(yv)
        if (it >= 2) {
            const int yy = yv - 1;
            unsigned h = (sm2.x != S.x ? 1u : 0u) | (sm2.y != S.y ? 2u : 0u)
                       | (sm2.z != S.z ? 4u : 0u) | (sm2.w != S.w ? 8u : 0u);
            if (h) {
                hits |= h;
                gminy = min(gminy, yy);
                gmaxy = yy;
            }
        }
        sm2 = sm1; sm1 = S;

        g[0] = g[1]; g[1] = g[2]; g[2] = g[3]; g[3] = g[4]; g[4] = nm;
        if (hasx) { ge[0] = ge[1]; ge[1] = ge[2]; ge[2] = ge[3]; ge[3] = ge[4]; ge[4] = ne; }
    }

    if (hits) {
        int lminx = cm + __ffs(hits) - 1;
        int lmaxx = cm + (31 - __clz(hits));
        atomicMin(&s_miny, gminy); atomicMax(&s_maxy, gmaxy);
        atomicMin(&s_minx, lminx); atomicMax(&s_maxx, lmaxx);
    }
    __syncthreads();
    if (tid == 0 && s_maxy >= 0) {
        atomicMin(&ws[0], s_miny);
        atomicMax(&ws[1], s_maxy);
        atomicMin(&ws[2], s_minx);
        atomicMax(&ws[3], s_maxx);
    }
}

__global__ void finalize(const int* __restrict__ ws, float* __restrict__ out) {
    int ymin = ws[0], ymax = ws[1], xmin = ws[2], xmax = ws[3];
    if (ymax < 0) {
        out[0] = 0.f; out[1] = 0.f; out[2] = 0.f; out[3] = 0.f;
    } else {
        // dilation by 2 (clipped), then ref's exclusive max (+1)
        out[0] = (float)(xmin - 2 > 0 ? xmin - 2 : 0);
        out[1] = (float)(ymin - 2 > 0 ? ymin - 2 : 0);
        out[2] = (float)((xmax + 2 < W - 1 ? xmax + 2 : W - 1) + 1);
        out[3] = (float)((ymax + 2 < H - 1 ? ymax + 2 : H - 1) + 1);
    }
}

extern "C" void kernel_launch(void* const* d_in, const int* in_sizes, int n_in,
                              void* d_out, int out_size, void* d_ws, size_t ws_size,
                              hipStream_t stream) {
    const float* xp = (const float*)d_in[0];   // (1,3,4096,4096) fp32
    const float* gw = (const float*)d_in[1];   // (3,) gray weights
    int*   ws  = (int*)d_ws;
    float* out = (float*)d_out;

    init_ws<<<1, 1, 0, stream>>>(ws);
    dim3 grid(W / (4 * WCOLS), H / TROWS);  // 4 x 256 = 1024 blocks, 4096 waves
    edge_kernel<<<grid, NT, 0, stream>>>(xp, gw, ws);
    finalize<<<1, 1, 0, stream>>>(ws, out);
}